// Round 1
// baseline (814.492 us; speedup 1.0000x reference)
//
#include <hip/hip_runtime.h>

// Problem constants (fixed by reference)
#define T     4
#define WQ    75
#define WS    25
#define C     640
#define HW    100
#define WAY   5
#define SHOT  5

// Tiling
#define CT    128          // c-tile edge
#define NT    5            // C / CT
#define NPAIR 15           // NT*(NT+1)/2 upper-tri tile pairs
#define KC    50           // k-chunk (LDS depth)
#define LS    132          // LDS row stride in floats (CT + 4 pad, keeps 16B align)
#define QC    5            // queries per block in score kernel

// ws layout (bytes):
//   cov   : [0, 32768000)            20 * 640*640 * 4   (Cov/99, upper tiles valid)
//   qmean : [32768000, 33536000)     300 * 640 * 4
//   smean : [33536000, 33587200)     20 * 640 * 4
#define WS_COV_OFF   0
#define WS_QMEAN_OFF 32768000
#define WS_SMEAN_OFF 33536000

__device__ __forceinline__ void pair_ij(int p, int& ti, int& tj) {
    int base = 0;
    #pragma unroll
    for (int a = 0; a < NT; ++a) {
        int cnt = NT - a;
        if (p < base + cnt) { ti = a; tj = a + (p - base); return; }
        base += cnt;
    }
    ti = 0; tj = 0;
}

__global__ void init_out_kernel(float* __restrict__ out, const float* __restrict__ bias) {
    int i = blockIdx.x * blockDim.x + threadIdx.x;
    if (i < T * WQ * WAY) out[i] = bias[0];
}

// qmean[t,q,c] over hw ; smean[t,w,c] over shot*hw
__global__ void means_kernel(const float* __restrict__ qf, const float* __restrict__ sf,
                             float* __restrict__ qmean, float* __restrict__ smean) {
    int i = blockIdx.x * blockDim.x + threadIdx.x;
    if (i < T * WQ * C) {
        const float4* p = (const float4*)(qf + (size_t)i * HW);
        float acc = 0.f;
        #pragma unroll
        for (int f = 0; f < HW / 4; ++f) { float4 v = p[f]; acc += v.x + v.y + v.z + v.w; }
        qmean[i] = acc * (1.0f / HW);
    } else if (i < T * WQ * C + T * WAY * C) {
        int j = i - T * WQ * C;
        int c = j % C; int tw = j / C;      // tw = t*WAY + w
        float acc = 0.f;
        for (int sh = 0; sh < SHOT; ++sh) {
            const float4* p = (const float4*)(sf + ((size_t)(tw * SHOT + sh) * C + c) * HW);
            #pragma unroll
            for (int f = 0; f < HW / 4; ++f) { float4 v = p[f]; acc += v.x + v.y + v.z + v.w; }
        }
        smean[j] = acc * (1.0f / (SHOT * HW));
    }
}

// Cov'[t,w] = (Sc^T Sc)/99 for upper 128x128 tile pairs. grid = (NPAIR, T*WAY)
__global__ __launch_bounds__(256, 2)
void cov_kernel(const float* __restrict__ sf, const float* __restrict__ smean,
                float* __restrict__ cov) {
    __shared__ float As[KC][LS];
    __shared__ float Bs[KC][LS];
    __shared__ float smA[CT];
    __shared__ float smB[CT];

    int p  = blockIdx.x;
    int tw = blockIdx.y;                 // t*WAY + w
    int ti, tj; pair_ij(p, ti, tj);
    int tid = threadIdx.x;
    int tx = tid & 15, ty = tid >> 4;

    if (tid < CT) smA[tid] = smean[tw * C + ti * CT + tid];
    else          smB[tid - CT] = smean[tw * C + tj * CT + (tid - CT)];

    float acc[8][8] = {};
    for (int sh = 0; sh < SHOT; ++sh) {
        const float* baseA = sf + ((size_t)(tw * SHOT + sh) * C + ti * CT) * HW;
        const float* baseB = sf + ((size_t)(tw * SHOT + sh) * C + tj * CT) * HW;
        for (int kc = 0; kc < HW; kc += KC) {
            __syncthreads();             // also orders smA/smB on first pass
            for (int f = tid; f < CT * (KC / 2); f += 256) {
                int row = f & (CT - 1);
                int fi  = f >> 7;        // 0..24
                int n   = kc + fi * 2;
                float  ma = smA[row];
                float2 va = *(const float2*)(baseA + row * HW + n);
                As[fi * 2 + 0][row] = va.x - ma;
                As[fi * 2 + 1][row] = va.y - ma;
                float  mb = smB[row];
                float2 vb = *(const float2*)(baseB + row * HW + n);
                Bs[fi * 2 + 0][row] = vb.x - mb;
                Bs[fi * 2 + 1][row] = vb.y - mb;
            }
            __syncthreads();
            #pragma unroll 2
            for (int k = 0; k < KC; ++k) {
                float4 a0 = *(const float4*)&As[k][ty * 8];
                float4 a1 = *(const float4*)&As[k][ty * 8 + 4];
                float4 b0 = *(const float4*)&Bs[k][tx * 8];
                float4 b1 = *(const float4*)&Bs[k][tx * 8 + 4];
                float a[8] = {a0.x, a0.y, a0.z, a0.w, a1.x, a1.y, a1.z, a1.w};
                float b[8] = {b0.x, b0.y, b0.z, b0.w, b1.x, b1.y, b1.z, b1.w};
                #pragma unroll
                for (int r = 0; r < 8; ++r)
                    #pragma unroll
                    for (int s = 0; s < 8; ++s)
                        acc[r][s] += a[r] * b[s];
            }
        }
    }

    const float inv = 1.0f / (HW - 1);
    float* cbase = cov + (size_t)tw * C * C + (size_t)(ti * CT + ty * 8) * C + tj * CT + tx * 8;
    #pragma unroll
    for (int r = 0; r < 8; ++r) {
        float4 o0 = {acc[r][0] * inv, acc[r][1] * inv, acc[r][2] * inv, acc[r][3] * inv};
        float4 o1 = {acc[r][4] * inv, acc[r][5] * inv, acc[r][6] * inv, acc[r][7] * inv};
        *(float4*)(cbase + (size_t)r * C)     = o0;
        *(float4*)(cbase + (size_t)r * C + 4) = o1;
    }
}

// Fused: M_tq tile (weighted centered Gram of query) dotted with 5 Cov tiles.
// grid = (NPAIR, T, WQ/QC); score[t,q,w] += mult * <Cov_tile, M_tile>
__global__ __launch_bounds__(256, 2)
void score_kernel(const float* __restrict__ qf, const float* __restrict__ qmean,
                  const float* __restrict__ cov, const float* __restrict__ convw,
                  float* __restrict__ out) {
    __shared__ float As[KC][LS];
    __shared__ float Bs[KC][LS];
    __shared__ float wl[HW];
    __shared__ float qmA[CT];
    __shared__ float qmB[CT];
    __shared__ float red[4][WAY];

    int p  = blockIdx.x;
    int t  = blockIdx.y;
    int qc = blockIdx.z;
    int ti, tj; pair_ij(p, ti, tj);
    int tid = threadIdx.x;
    int tx = tid & 15, ty = tid >> 4;
    int lane = tid & 63, wv = tid >> 6;

    if (tid < HW) wl[tid] = convw[tid];
    float mult = (ti == tj) ? 1.0f : 2.0f;

    for (int qi = 0; qi < QC; ++qi) {
        int q = qc * QC + qi;
        __syncthreads();                 // protect qmA/qmB/red from previous iter
        if (tid < CT) qmA[tid] = qmean[(size_t)(t * WQ + q) * C + ti * CT + tid];
        else          qmB[tid - CT] = qmean[(size_t)(t * WQ + q) * C + tj * CT + (tid - CT)];

        float acc[8][8] = {};
        const float* baseA = qf + ((size_t)(t * WQ + q) * C + ti * CT) * HW;
        const float* baseB = qf + ((size_t)(t * WQ + q) * C + tj * CT) * HW;
        for (int kc = 0; kc < HW; kc += KC) {
            __syncthreads();
            for (int f = tid; f < CT * (KC / 2); f += 256) {
                int row = f & (CT - 1);
                int fi  = f >> 7;
                int n   = kc + fi * 2;
                float  ma = qmA[row];
                float2 va = *(const float2*)(baseA + row * HW + n);
                As[fi * 2 + 0][row] = (va.x - ma) * wl[n];
                As[fi * 2 + 1][row] = (va.y - ma) * wl[n + 1];
                float  mb = qmB[row];
                float2 vb = *(const float2*)(baseB + row * HW + n);
                Bs[fi * 2 + 0][row] = vb.x - mb;
                Bs[fi * 2 + 1][row] = vb.y - mb;
            }
            __syncthreads();
            #pragma unroll 2
            for (int k = 0; k < KC; ++k) {
                float4 a0 = *(const float4*)&As[k][ty * 8];
                float4 a1 = *(const float4*)&As[k][ty * 8 + 4];
                float4 b0 = *(const float4*)&Bs[k][tx * 8];
                float4 b1 = *(const float4*)&Bs[k][tx * 8 + 4];
                float a[8] = {a0.x, a0.y, a0.z, a0.w, a1.x, a1.y, a1.z, a1.w};
                float b[8] = {b0.x, b0.y, b0.z, b0.w, b1.x, b1.y, b1.z, b1.w};
                #pragma unroll
                for (int r = 0; r < 8; ++r)
                    #pragma unroll
                    for (int s = 0; s < 8; ++s)
                        acc[r][s] += a[r] * b[s];
            }
        }

        // Dot the in-register M tile with the 5 ways' Cov tiles (L2-resident)
        float sums[WAY];
        const float* cb0 = cov + (size_t)(t * WAY) * C * C
                         + (size_t)(ti * CT + ty * 8) * C + tj * CT + tx * 8;
        #pragma unroll
        for (int w = 0; w < WAY; ++w) {
            const float* cb = cb0 + (size_t)w * C * C;
            float s = 0.f;
            #pragma unroll
            for (int r = 0; r < 8; ++r) {
                float4 c0 = *(const float4*)(cb + (size_t)r * C);
                float4 c1 = *(const float4*)(cb + (size_t)r * C + 4);
                s += acc[r][0] * c0.x + acc[r][1] * c0.y + acc[r][2] * c0.z + acc[r][3] * c0.w
                   + acc[r][4] * c1.x + acc[r][5] * c1.y + acc[r][6] * c1.z + acc[r][7] * c1.w;
            }
            sums[w] = s * mult;
        }

        #pragma unroll
        for (int w = 0; w < WAY; ++w) {
            float v = sums[w];
            #pragma unroll
            for (int off = 32; off > 0; off >>= 1) v += __shfl_down(v, off);
            if (lane == 0) red[wv][w] = v;
        }
        __syncthreads();
        if (tid < WAY) {
            float tot = red[0][tid] + red[1][tid] + red[2][tid] + red[3][tid];
            atomicAdd(&out[(size_t)(t * WQ + q) * WAY + tid], tot);
        }
    }
}

extern "C" void kernel_launch(void* const* d_in, const int* in_sizes, int n_in,
                              void* d_out, int out_size, void* d_ws, size_t ws_size,
                              hipStream_t stream) {
    const float* qf = (const float*)d_in[0];   // (4,75,640,10,10)
    const float* sf = (const float*)d_in[1];   // (4,25,640,10,10)
    const float* cw = (const float*)d_in[2];   // (1,1,100)
    const float* cb = (const float*)d_in[3];   // (1,)
    float* out = (float*)d_out;                // (4,75,5)

    float* cov   = (float*)((char*)d_ws + WS_COV_OFF);
    float* qmean = (float*)((char*)d_ws + WS_QMEAN_OFF);
    float* smean = (float*)((char*)d_ws + WS_SMEAN_OFF);

    init_out_kernel<<<(T * WQ * WAY + 255) / 256, 256, 0, stream>>>(out, cb);
    means_kernel<<<(T * WQ * C + T * WAY * C + 255) / 256, 256, 0, stream>>>(qf, sf, qmean, smean);
    cov_kernel<<<dim3(NPAIR, T * WAY), 256, 0, stream>>>(sf, smean, cov);
    score_kernel<<<dim3(NPAIR, T, WQ / QC), 256, 0, stream>>>(qf, qmean, cov, cw, out);
}